// Round 13
// baseline (74.742 us; speedup 1.0000x reference)
//
#include <hip/hip_runtime.h>
#include <math.h>

typedef unsigned int uint;
typedef unsigned long long u64;

constexpr int BATCH = 16;
constexpr int HW_TOTAL = 21824;     // 16384+4096+1024+256+64
constexpr int NCAND = 3320;         // 1000+1000+1000+256+64
constexpr int MAXDET = 100;

// workspace layout in 4-byte units
constexpr int FULL_KEY  = 0;                                  // u32 keys (score bits - 0x3D000000; 0 = dead)
constexpr int FULL_CLS  = FULL_KEY + BATCH * HW_TOTAL;        // 349184 (f32)
constexpr int FULL_PBOX = FULL_CLS + BATCH * HW_TOTAL;        // 698368 (uint2: x1|y1<<16, x2|y2<<16)
constexpr int CAND_KEY  = FULL_PBOX + BATCH * HW_TOTAL * 2;   // 1396736
constexpr int CAND_CLS  = CAND_KEY + BATCH * NCAND;           // 1449856
constexpr int CAND_PBOX = CAND_CLS + BATCH * NCAND;           // 1502976 (uint2)

struct Ptrs {
  const float* cls0; const float* reg0; const float* ctr0;
  const float* cls1; const float* reg1; const float* ctr1;
  const float* cls2; const float* reg2; const float* ctr2;
  const float* cls3; const float* reg3; const float* ctr3;
  const float* cls4; const float* reg4; const float* ctr4;
};

__device__ __forceinline__ float sigmoidf_(float x) { return 1.f / (1.f + expf(-x)); }

// packed 2x16 int ops (coords in [0,1023] -> i16-safe; widths always >= 0 for this decode)
__device__ __forceinline__ uint pk_max16(uint a, uint b){ uint d; asm("v_pk_max_i16 %0, %1, %2" : "=v"(d) : "v"(a), "v"(b)); return d; }
__device__ __forceinline__ uint pk_min16(uint a, uint b){ uint d; asm("v_pk_min_i16 %0, %1, %2" : "=v"(d) : "v"(a), "v"(b)); return d; }
__device__ __forceinline__ uint pk_sub16(uint a, uint b){ uint d; asm("v_pk_sub_i16 %0, %1, %2" : "=v"(d) : "v"(a), "v"(b)); return d; }
__device__ __forceinline__ uint mul24(uint a, uint b){ uint d; asm("v_mul_u32_u24 %0, %1, %2" : "=v"(d) : "v"(a), "v"(b)); return d; }

__device__ __forceinline__ void scan4(float4 q, int kbase, float& M, float& M2, int& mi)
{
  float v; bool c;
  v = q.x; c = v > M; M2 = c ? M : fmaxf(M2, v); M = c ? v : M; mi = c ? kbase + 0 : mi;
  v = q.y; c = v > M; M2 = c ? M : fmaxf(M2, v); M = c ? v : M; mi = c ? kbase + 1 : mi;
  v = q.z; c = v > M; M2 = c ? M : fmaxf(M2, v); M = c ? v : M; mi = c ? kbase + 2 : mi;
  v = q.w; c = v > M; M2 = c ? M : fmaxf(M2, v); M = c ? v : M; mi = c ? kbase + 3 : mi;
}

// 8 LANES per position, no LDS. Lane 8g+r loads float4s {r, r+8} (+ {16+r}
// for r<4, exec-masked): per-instruction segments are 128B-contiguous per
// row, rows 320B apart (coalescing == round-11). 2x waves vs round-11
// (43648), ~35 VALU/lane, 2-3 independent loads/lane. Group leader issues
// its reg/ctr loads BEFORE the cls scan so that HBM round-trip overlaps.
// Merge (M, M2, first-index argmax) over 8 lanes = 3 shfl_xor steps:
// per-lane index sets are disjoint & ascending-scanned, tie -> min index ==
// reference first-index; equal lane-maxes give M2=M -> exact slow path.
// Sigmoid fast path (validated bit-exact rounds 7-12): logit argmax ==
// sigmoid argmax unless M2 within 8e-6/(1-s*) of M; rare fallback = exact
// reference-order sigmoid argmax on register-resident bufs, merged with
// (larger s, tie -> smaller idx).
__global__ __launch_bounds__(256) void decode_kernel(Ptrs p, uint* wsu)
{
  const int t = threadIdx.x;
  const int wv = t >> 6, lane = t & 63;
  const int g = lane >> 3, r = lane & 7;
  const int wpos0 = blockIdx.x * 32 + wv * 8;     // wave's first position
  const int b = wpos0 / HW_TOTAL;
  const int hw0 = wpos0 - b * HW_TOTAL;           // wave-uniform level (8-pos aligned)

  const float *clsp, *regp, *ctrp;
  int lstart, lw, HWl; float stridef;
  if (hw0 < 16384)      { lstart = 0;     lw = 7; stridef = 8.f;   HWl = 16384; clsp = p.cls0; regp = p.reg0; ctrp = p.ctr0; }
  else if (hw0 < 20480) { lstart = 16384; lw = 6; stridef = 16.f;  HWl = 4096;  clsp = p.cls1; regp = p.reg1; ctrp = p.ctr1; }
  else if (hw0 < 21504) { lstart = 20480; lw = 5; stridef = 32.f;  HWl = 1024;  clsp = p.cls2; regp = p.reg2; ctrp = p.ctr2; }
  else if (hw0 < 21760) { lstart = 21504; lw = 4; stridef = 64.f;  HWl = 256;   clsp = p.cls3; regp = p.reg3; ctrp = p.ctr3; }
  else                  { lstart = 21760; lw = 3; stridef = 128.f; HWl = 64;    clsp = p.cls4; regp = p.reg4; ctrp = p.ctr4; }

  const long base = (long)b * HWl + (hw0 - lstart);   // level-local of wave's first pos
  const long row = base + g;                          // this group's level-local row
  const float4* c4 = reinterpret_cast<const float4*>(clsp) + row * 20;

  // leader's reg/ctr issued FIRST: latency overlaps the cls scan below
  float4 r4 = make_float4(0.f, 0.f, 0.f, 0.f);
  float ctrv = 0.f;
  if (r == 0) {
    r4 = reinterpret_cast<const float4*>(regp)[row];
    ctrv = ctrp[row];
  }

  // 2-3 independent loads; lane covers classes {4r..}, {4(r+8)..}, {4(16+r)..}
  float4 buf0 = c4[r];
  float4 buf1 = c4[r + 8];
  float4 buf2 = make_float4(0.f, 0.f, 0.f, 0.f);
  if (r < 4) buf2 = c4[16 + r];

  float M = -INFINITY, M2 = -INFINITY; int mi = 0;
  scan4(buf0, 4 * r, M, M2, mi);
  scan4(buf1, 4 * (r + 8), M, M2, mi);
  if (r < 4) scan4(buf2, 4 * (16 + r), M, M2, mi);

  // merge (M, M2, mi) across the 8 lanes of the group (xor 1, 2, 4)
  #pragma unroll
  for (int ms_ = 1; ms_ <= 4; ms_ <<= 1) {
    float Mo  = __shfl_xor(M, ms_);
    float M2o = __shfl_xor(M2, ms_);
    int   mio = __shfl_xor(mi, ms_);
    float mn = fminf(M, Mo);
    M2 = fmaxf(mn, fmaxf(M2, M2o));                 // equal maxes -> M2 = M -> slow path
    bool take = (Mo > M) || (Mo == M && mio < mi);  // tie -> min index (first index)
    mi = take ? mio : mi;
    M  = fmaxf(M, Mo);
  }

  float sstar = sigmoidf_(M);
  float onem = 1.0f - sstar;
  float thr = (onem > 0.0f) ? (M - 8e-6f / onem) : INFINITY;   // INF -> forced slow path
  float msig = sstar; int mfin = mi;
  if (!(M2 < thr)) {
    // exact path: per-lane in-order sigmoid argmax (strict >), cross-lane
    // merge (larger s; tie -> smaller idx) == reference global first-index
    float ms = -1.f; int mj = 0;
    {
      float s;
      int kb = 4 * r;
      s = sigmoidf_(buf0.x); if (s > ms) { ms = s; mj = kb + 0; }
      s = sigmoidf_(buf0.y); if (s > ms) { ms = s; mj = kb + 1; }
      s = sigmoidf_(buf0.z); if (s > ms) { ms = s; mj = kb + 2; }
      s = sigmoidf_(buf0.w); if (s > ms) { ms = s; mj = kb + 3; }
      kb = 4 * (r + 8);
      s = sigmoidf_(buf1.x); if (s > ms) { ms = s; mj = kb + 0; }
      s = sigmoidf_(buf1.y); if (s > ms) { ms = s; mj = kb + 1; }
      s = sigmoidf_(buf1.z); if (s > ms) { ms = s; mj = kb + 2; }
      s = sigmoidf_(buf1.w); if (s > ms) { ms = s; mj = kb + 3; }
      if (r < 4) {
        kb = 4 * (16 + r);
        s = sigmoidf_(buf2.x); if (s > ms) { ms = s; mj = kb + 0; }
        s = sigmoidf_(buf2.y); if (s > ms) { ms = s; mj = kb + 1; }
        s = sigmoidf_(buf2.z); if (s > ms) { ms = s; mj = kb + 2; }
        s = sigmoidf_(buf2.w); if (s > ms) { ms = s; mj = kb + 3; }
      }
    }
    #pragma unroll
    for (int ms_ = 1; ms_ <= 4; ms_ <<= 1) {
      float mso = __shfl_xor(ms, ms_);
      int   mjo = __shfl_xor(mj, ms_);
      bool take = (mso > ms) || (mso == ms && mjo < mj);
      ms = take ? mso : ms;
      mj = take ? mjo : mj;
    }
    msig = ms; mfin = mj;
  }

  if (r == 0) {                       // group leader finishes the position
    float scv = sqrtf(msig * sigmoidf_(ctrv));

    int lhw = (hw0 - lstart) + g;
    int h = lhw >> lw, w = lhw - (h << lw);
    float x = ((float)w + 0.5f) * stridef;
    float y = ((float)h + 0.5f) * stridef;
    float x1 = fmaxf(truncf(x - expf(r4.x)), 0.f);
    float y1 = fmaxf(truncf(y - expf(r4.y)), 0.f);
    float x2 = fminf(truncf(x + expf(r4.z)), 1023.f);
    float y2 = fminf(truncf(y + expf(r4.w)), 1023.f);

    // key: monotone u26 form of score; 0 = dead (masking pre-topk is output-equivalent)
    uint kraw = (scv > 0.05f) ? (__float_as_uint(scv) - 0x3D000000u) : 0u;
    uint ix1 = (uint)x1, iy1 = (uint)y1, ix2 = (uint)x2, iy2 = (uint)y2;
    uint2 pb = make_uint2(ix1 | (iy1 << 16), ix2 | (iy2 << 16));

    int idx = wpos0 + g;
    int hw = hw0 + g;
    float* wsf = (float*)wsu;
    wsu[FULL_KEY + idx] = kraw;
    wsf[FULL_CLS + idx] = (float)mfin;
    reinterpret_cast<uint2*>(wsu + FULL_PBOX)[idx] = pb;

    // levels 3/4 skip top-k (HW < TOP_N): write candidate slices directly
    if (hw >= 21504) {
      int ci = b * NCAND + 3000 + (hw - 21504);
      wsu[CAND_KEY + ci] = kraw;
      wsf[CAND_CLS + ci] = (float)mfin;
      reinterpret_cast<uint2*>(wsu + CAND_PBOX)[ci] = pb;
    }
  }
}

// exclusive block scan over 1024 threads; also returns grand total.
// Internal barriers; safe to call repeatedly (barrier precedes partials write).
__device__ __forceinline__ uint block_scan_excl(uint v, uint* partials, uint& total)
{
  int lane = threadIdx.x & 63, wv = threadIdx.x >> 6;
  uint incl = v;
  #pragma unroll
  for (int m = 1; m < 64; m <<= 1) {
    uint u = __shfl_up(incl, m);
    if (lane >= m) incl += u;
  }
  __syncthreads();
  if (lane == 63) partials[wv] = incl;
  __syncthreads();
  uint wpre = 0, tot = 0;
  #pragma unroll
  for (int w = 0; w < 16; ++w) {
    uint pv = partials[w];
    if (w < wv) wpre += pv;
    tot += pv;
  }
  total = tot;
  return wpre + incl - v;
}

// exact top-k per (batch, level): keys register-resident; exact K-th-largest
// key via 2-pass 13-bit radix-select (~14 block barriers); then >lo all +
// ==lo in index order (== lax.top_k set). Radix lo == binary-search lo
// (dead keys participate as value 0).
template<int CH, int HW, int K>
__device__ void topk_impl(const uint* __restrict__ fsu, const float* __restrict__ fc,
                          const uint2* __restrict__ fpb,
                          uint* __restrict__ cs, float* __restrict__ cc,
                          uint2* __restrict__ cpb,
                          uint* scratch, uint* partials, int* part, uint* selsh)
{
  int t = threadIdx.x, lane = t & 63, wid = t >> 6;

  uint key[CH];
  constexpr int HALF = (HW > 8192) ? 8192 : HW;   // staging tile (<= 32KB LDS)
  constexpr int ROUNDS = HW / HALF;
  #pragma unroll
  for (int rr = 0; rr < ROUNDS; ++rr) {
    int base = rr * HALF;
    for (int i = t; i < HALF; i += 1024)          // coalesced global read
      scratch[i] = fsu[base + i];
    __syncthreads();
    int t0 = base / CH;
    if (t >= t0 && t < t0 + HALF / CH) {          // redistribute: contiguous chunk per thread
      int off = t * CH - base;
      #pragma unroll
      for (int k = 0; k < CH; ++k) key[k] = scratch[off + k];
    }
    __syncthreads();
  }

  // ---- radix-select: lo = exact K-th largest key (keys are 26-bit) ----
  // pass 1: histogram of key>>13 (buckets 0..8191); reversed scan -> bucket T
  for (int i = t; i < 8192; i += 1024) scratch[i] = 0u;
  __syncthreads();
  #pragma unroll
  for (int k = 0; k < CH; ++k) atomicAdd(&scratch[key[k] >> 13], 1u);
  __syncthreads();
  uint c8[8], s = 0;
  #pragma unroll
  for (int j = 0; j < 8; ++j) { c8[j] = scratch[8191 - (t * 8 + j)]; s += c8[j]; }
  uint total;
  uint cum = block_scan_excl(s, partials, total);  // count in buckets above mine
  #pragma unroll
  for (int j = 0; j < 8; ++j) {                    // exactly one thread crosses
    if (cum < (uint)K && cum + c8[j] >= (uint)K) {
      selsh[0] = (uint)(8191 - (t * 8 + j));       // T
      selsh[1] = cum;                              // count of keys with prefix > T
    }
    cum += c8[j];
  }
  __syncthreads();                                 // selsh visible; pass-1 reads done
  const uint T = selsh[0];
  const uint Kp = (uint)K - selsh[1];              // rank within bucket T (1-based)

  // pass 2: histogram of low 13 bits within bucket T; reversed scan -> L
  for (int i = t; i < 8192; i += 1024) scratch[i] = 0u;
  __syncthreads();
  #pragma unroll
  for (int k = 0; k < CH; ++k)
    if ((key[k] >> 13) == T) atomicAdd(&scratch[key[k] & 0x1FFFu], 1u);
  __syncthreads();
  uint d8[8], s2 = 0;
  #pragma unroll
  for (int j = 0; j < 8; ++j) { d8[j] = scratch[8191 - (t * 8 + j)]; s2 += d8[j]; }
  uint tot2;
  uint cum2 = block_scan_excl(s2, partials, tot2);
  #pragma unroll
  for (int j = 0; j < 8; ++j) {
    if (cum2 < Kp && cum2 + d8[j] >= Kp) selsh[2] = (uint)(8191 - (t * 8 + j));
    cum2 += d8[j];
  }
  __syncthreads();
  const uint lo = (T << 13) | selsh[2];

  // ranks: count(>lo) all selected (index order), then ==lo fills to K (index order)
  int cgt = 0, ceq = 0;
  #pragma unroll
  for (int k = 0; k < CH; ++k) { cgt += (key[k] > lo) ? 1 : 0; ceq += (key[k] == lo) ? 1 : 0; }
  uint packed = ((uint)cgt << 16) | (uint)ceq;
  uint incl = packed;
  #pragma unroll
  for (int m = 1; m < 64; m <<= 1) {
    uint u = __shfl_up(incl, m);
    if (lane >= m) incl += u;
  }
  __syncthreads();
  if (lane == 63) part[wid] = (int)incl;
  __syncthreads();
  uint wpre = 0, tot_all = 0;
  #pragma unroll
  for (int w = 0; w < 16; ++w) {
    uint pv = (uint)part[w];
    if (w < wid) wpre += pv;
    tot_all += pv;
  }
  uint excl = wpre + incl - packed;
  int rgt = (int)(excl >> 16);
  int req = (int)(tot_all >> 16) + (int)(excl & 0xFFFFu);

  #pragma unroll
  for (int k = 0; k < CH; ++k) {
    int i = t * CH + k;
    uint kk = key[k];
    int r = -1;
    if (kk > lo) r = rgt++;
    else if (kk == lo) r = req++;
    if (r >= 0 && r < K) {
      cs[r] = kk;
      cc[r] = fc[i];
      cpb[r] = fpb[i];
    }
  }
}

__global__ __launch_bounds__(1024) void topk_kernel(uint* wsu)
{
  __shared__ uint scratch[8192];   // staging, then radix histograms (32 KB)
  __shared__ uint partials[16];
  __shared__ int part[16];
  __shared__ uint selsh[4];
  int b = blockIdx.x, lvl = blockIdx.y;
  int lstart, coff;
  if (lvl == 0)      { lstart = 0;     coff = 0;    }
  else if (lvl == 1) { lstart = 16384; coff = 1000; }
  else               { lstart = 20480; coff = 2000; }
  int fbase = b * HW_TOTAL + lstart;
  const uint* fsu = wsu + FULL_KEY + fbase;
  const float* fc = ((const float*)wsu) + FULL_CLS + fbase;
  const uint2* fpb = reinterpret_cast<const uint2*>(wsu + FULL_PBOX) + fbase;
  uint*  cs = wsu + CAND_KEY + b * NCAND + coff;
  float* cc = ((float*)wsu) + CAND_CLS + b * NCAND + coff;
  uint2* cpb = reinterpret_cast<uint2*>(wsu + CAND_PBOX) + b * NCAND + coff;

  if (lvl == 0)      topk_impl<16, 16384, 1000>(fsu, fc, fpb, cs, cc, cpb, scratch, partials, part, selsh);
  else if (lvl == 1) topk_impl<4,  4096,  1000>(fsu, fc, fpb, cs, cc, cpb, scratch, partials, part, selsh);
  else               topk_impl<1,  1024,  1000>(fsu, fc, fpb, cs, cc, cpb, scratch, partials, part, selsh);
}

// ---- bitonic helpers ----
__device__ __forceinline__ u64 shfl_xor_u64(u64 v, int m) {
  int lo = __shfl_xor((int)(uint)(v & 0xffffffffull), m);
  int hi = __shfl_xor((int)(uint)(v >> 32), m);
  return ((u64)(uint)hi << 32) | (u64)(uint)lo;
}
__device__ __forceinline__ u64 ce_shfl(u64 v, int j, bool up, int lane) {
  u64 p = shfl_xor_u64(v, j);
  bool keep_max = (((lane & j) == 0) == up);
  return keep_max ? (v > p ? v : p) : (v < p ? v : p);
}
__device__ __forceinline__ u64 ce_lds(u64 v, u64 p, uint i, uint j, uint k) {
  bool keep_max = (((i & j) == 0u) == ((i & k) == 0u));
  return keep_max ? (v > p ? v : p) : (v < p ? v : p);
}

// Preselect + sort + lazy greedy NMS, one block per batch (round-6 design,
// passing absmax 0; see earlier round comments for the equivalence proofs).
__global__ __launch_bounds__(1024) void nms_kernel(const uint* __restrict__ wsu,
                                                   float* __restrict__ out)
{
  __shared__ uint hist[4096];      // 16 KB
  __shared__ u64 items[1024];      // 8 KB
  __shared__ uint2 boxo[3328];     // 26 KB, indexed by original slot
  __shared__ uint partials[16];
  __shared__ int bsel_sh;

  const int b = blockIdx.x, t = threadIdx.x;
  const int lane = t & 63;
  const uint*  ck  = wsu + CAND_KEY + b * NCAND;
  const float* ccl = ((const float*)wsu) + CAND_CLS + b * NCAND;
  const uint2* cpb = reinterpret_cast<const uint2*>(wsu + CAND_PBOX) + b * NCAND;

  // load keys (regs) + boxes (LDS), coalesced
  uint k0 = (t          < NCAND) ? ck[t]          : 0u;
  uint k1 = (t + 1024   < NCAND) ? ck[t + 1024]   : 0u;
  uint k2 = (t + 2048   < NCAND) ? ck[t + 2048]   : 0u;
  uint k3 = (t + 3072   < NCAND) ? ck[t + 3072]   : 0u;
  for (int i = t; i < 3328; i += 1024)
    boxo[i] = (i < NCAND) ? cpb[i] : make_uint2(0u, 0u);

  reinterpret_cast<uint4*>(hist)[t] = make_uint4(0u, 0u, 0u, 0u);
  if (t == 0) bsel_sh = 0;
  __syncthreads();

  if (k0) atomicAdd(&hist[k0 >> 14], 1u);
  if (k1) atomicAdd(&hist[k1 >> 14], 1u);
  if (k2) atomicAdd(&hist[k2 >> 14], 1u);
  if (k3) atomicAdd(&hist[k3 >> 14], 1u);
  __syncthreads();

  // reversed cumulative (from highest bucket down); find bucket of 512th key
  uint c[4]; uint s = 0;
  #pragma unroll
  for (int q = 0; q < 4; ++q) { c[q] = hist[4095 - (t * 4 + q)]; s += c[q]; }
  uint total;
  uint excl = block_scan_excl(s, partials, total);
  {
    uint cum = excl;
    #pragma unroll
    for (int q = 0; q < 4; ++q) {
      if (total >= 512u && cum < 512u && cum + c[q] >= 512u)
        bsel_sh = 4095 - (t * 4 + q);
      cum += c[q];
    }
  }
  __syncthreads();
  const uint B = (uint)bsel_sh;

  // compact the >=B slice into items[]
  bool s0 = k0 && (k0 >> 14) >= B;
  bool s1 = k1 && (k1 >> 14) >= B;
  bool s2 = k2 && (k2 >> 14) >= B;
  bool s3 = k3 && (k3 >> 14) >= B;
  uint nsel = (uint)s0 + (uint)s1 + (uint)s2 + (uint)s3;
  items[t] = 0ull;
  uint tot2;
  uint pos = block_scan_excl(nsel, partials, tot2);
  if (s0) { if (pos < 1024u) items[pos] = ((u64)k0 << 32) | (u64)(0xFFFFu - (uint)t);          ++pos; }
  if (s1) { if (pos < 1024u) items[pos] = ((u64)k1 << 32) | (u64)(0xFFFFu - (uint)(t + 1024)); ++pos; }
  if (s2) { if (pos < 1024u) items[pos] = ((u64)k2 << 32) | (u64)(0xFFFFu - (uint)(t + 2048)); ++pos; }
  if (s3) { if (pos < 1024u) items[pos] = ((u64)k3 << 32) | (u64)(0xFFFFu - (uint)(t + 3072)); ++pos; }
  __syncthreads();

  // bitonic sort of 1024 items, descending; 1 item/thread
  u64 r = items[t];
  for (uint kk = 2; kk <= 1024; kk <<= 1) {
    for (uint j = kk >> 1; j > 0; j >>= 1) {
      if (j >= 64u) {
        items[t] = r;
        __syncthreads();
        u64 p = items[t ^ (int)j];
        r = ce_lds(r, p, (uint)t, j, kk);
        __syncthreads();
      } else {
        r = ce_shfl(r, (int)j, ((uint)t & kk) == 0u, lane);
      }
    }
  }
  items[t] = r;
  __syncthreads();

  if (t >= 64) return;               // scan + writeout are wave-0 only

  uint sax = 0u, say = 0u, sa3a = 0u;     // selected box (index == lane)
  uint sbx = 0u, sby = 0u, sa3b = 0u;     // selected box (index == 64+lane)
  uint rrank0 = 0xFFFFFFFFu, rrank1 = 0xFFFFFFFFu;
  int m = 0;
  bool done = false;

  for (int base = 0; base < 1024 && !done && m < MAXDET; base += 64) {
    u64 it = items[base + lane];
    uint mykey = (uint)(it >> 32);
    int myslot = 0xFFFF - (int)(it & 0xFFFFu);
    if (myslot > 3327) myslot = 0;         // dead lanes: clamp (value unused)
    uint2 mb = boxo[myslot];
    uint mwh = pk_sub16(mb.y, mb.x);
    uint mqa3 = 3u * mul24(mwh & 0xffffu, mwh >> 16);

    u64 deadmask = __ballot(mykey == 0u);  // sorted: dead lanes are a suffix
    int nv = deadmask ? (__ffsll((long long)deadmask) - 1) : 64;
    if (nv < 64) done = true;

    for (int s = 0; s < nv; ++s) {
      uint qx  = (uint)__builtin_amdgcn_readlane((int)mb.x, s);
      uint qy  = (uint)__builtin_amdgcn_readlane((int)mb.y, s);
      uint qa3 = (uint)__builtin_amdgcn_readlane((int)mqa3, s);

      uint tl = pk_max16(qx, sax), br = pk_min16(qy, say);
      uint wh = pk_max16(pk_sub16(br, tl), 0u);
      uint inter = mul24(wh & 0xffffu, wh >> 16);
      uint s3 = qa3 + sa3a; uint s3m = s3 > 1u ? s3 : 1u;
      bool sup0 = (lane < m) && ((inter << 3) >= s3m);

      tl = pk_max16(qx, sbx); br = pk_min16(qy, sby);
      wh = pk_max16(pk_sub16(br, tl), 0u);
      inter = mul24(wh & 0xffffu, wh >> 16);
      s3 = qa3 + sa3b; s3m = s3 > 1u ? s3 : 1u;
      bool sup1 = ((64 + lane) < m) && ((inter << 3) >= s3m);

      if (__ballot(sup0 || sup1) == 0ull) {    // SELECT rank base+s
        int rank = base + s;
        if (m < 64) {
          if (lane == m)      { sax = qx; say = qy; sa3a = qa3; rrank0 = (uint)rank; }
        } else {
          if (lane == m - 64) { sbx = qx; sby = qy; sa3b = qa3; rrank1 = (uint)rank; }
        }
        ++m;
        if (m >= MAXDET) break;
      }
    }
  }

  // writeout: lane l -> detection l (rrank0) and 64+l (rrank1, l<36)
  float* outs = out;
  float* outc = out + BATCH * MAXDET;
  float4* outb = reinterpret_cast<float4*>(out + 2 * BATCH * MAXDET);
  {
    float s, cl; float4 bx;
    if (rrank0 != 0xFFFFFFFFu) {
      u64 it = items[rrank0];
      uint key = (uint)(it >> 32);
      int slot = 0xFFFF - (int)(it & 0xFFFFu);
      uint2 q = boxo[slot];
      s = __uint_as_float(key + 0x3D000000u);
      cl = ccl[slot];
      bx = make_float4((float)(q.x & 0xffffu), (float)(q.x >> 16),
                       (float)(q.y & 0xffffu), (float)(q.y >> 16));
    } else { s = -1.f; cl = -1.f; bx = make_float4(-1.f, -1.f, -1.f, -1.f); }
    outs[b * MAXDET + lane] = s;
    outc[b * MAXDET + lane] = cl;
    outb[b * MAXDET + lane] = bx;
  }
  if (lane < MAXDET - 64) {
    float s, cl; float4 bx;
    if (rrank1 != 0xFFFFFFFFu) {
      u64 it = items[rrank1];
      uint key = (uint)(it >> 32);
      int slot = 0xFFFF - (int)(it & 0xFFFFu);
      uint2 q = boxo[slot];
      s = __uint_as_float(key + 0x3D000000u);
      cl = ccl[slot];
      bx = make_float4((float)(q.x & 0xffffu), (float)(q.x >> 16),
                       (float)(q.y & 0xffffu), (float)(q.y >> 16));
    } else { s = -1.f; cl = -1.f; bx = make_float4(-1.f, -1.f, -1.f, -1.f); }
    outs[b * MAXDET + 64 + lane] = s;
    outc[b * MAXDET + 64 + lane] = cl;
    outb[b * MAXDET + 64 + lane] = bx;
  }
}

extern "C" void kernel_launch(void* const* d_in, const int* in_sizes, int n_in,
                              void* d_out, int out_size, void* d_ws, size_t ws_size,
                              hipStream_t stream)
{
  Ptrs p;
  p.cls0 = (const float*)d_in[0];  p.reg0 = (const float*)d_in[1];  p.ctr0 = (const float*)d_in[2];
  p.cls1 = (const float*)d_in[3];  p.reg1 = (const float*)d_in[4];  p.ctr1 = (const float*)d_in[5];
  p.cls2 = (const float*)d_in[6];  p.reg2 = (const float*)d_in[7];  p.ctr2 = (const float*)d_in[8];
  p.cls3 = (const float*)d_in[9];  p.reg3 = (const float*)d_in[10]; p.ctr3 = (const float*)d_in[11];
  p.cls4 = (const float*)d_in[12]; p.reg4 = (const float*)d_in[13]; p.ctr4 = (const float*)d_in[14];

  uint* wsu = (uint*)d_ws;
  float* out = (float*)d_out;

  // 8 lanes/position: 2793472 threads = 10912 blocks x 256
  decode_kernel<<<(8 * BATCH * HW_TOTAL) / 256, 256, 0, stream>>>(p, wsu);
  dim3 g2(BATCH, 3);
  topk_kernel<<<g2, 1024, 0, stream>>>(wsu);
  nms_kernel<<<BATCH, 1024, 0, stream>>>(wsu, out);
}

// Round 14
// 70.190 us; speedup vs baseline: 1.0649x; 1.0649x over previous
//
#include <hip/hip_runtime.h>
#include <math.h>

typedef unsigned int uint;
typedef unsigned long long u64;

constexpr int BATCH = 16;
constexpr int HW_TOTAL = 21824;     // 16384+4096+1024+256+64
constexpr int NCAND = 3320;         // 1000+1000+1000+256+64
constexpr int MAXDET = 100;

// workspace layout in 4-byte units
constexpr int FULL_KEY  = 0;                                  // u32 keys (score bits - 0x3D000000; 0 = dead)
constexpr int FULL_CLS  = FULL_KEY + BATCH * HW_TOTAL;        // 349184 (f32)
constexpr int FULL_PBOX = FULL_CLS + BATCH * HW_TOTAL;        // 698368 (uint2: x1|y1<<16, x2|y2<<16)
constexpr int CAND_KEY  = FULL_PBOX + BATCH * HW_TOTAL * 2;   // 1396736
constexpr int CAND_CLS  = CAND_KEY + BATCH * NCAND;           // 1449856
constexpr int CAND_PBOX = CAND_CLS + BATCH * NCAND;           // 1502976 (uint2)

struct Ptrs {
  const float* cls0; const float* reg0; const float* ctr0;
  const float* cls1; const float* reg1; const float* ctr1;
  const float* cls2; const float* reg2; const float* ctr2;
  const float* cls3; const float* reg3; const float* ctr3;
  const float* cls4; const float* reg4; const float* ctr4;
};

__device__ __forceinline__ float sigmoidf_(float x) { return 1.f / (1.f + expf(-x)); }

// packed 2x16 int ops (coords in [0,1023] -> i16-safe; widths always >= 0 for this decode)
__device__ __forceinline__ uint pk_max16(uint a, uint b){ uint d; asm("v_pk_max_i16 %0, %1, %2" : "=v"(d) : "v"(a), "v"(b)); return d; }
__device__ __forceinline__ uint pk_min16(uint a, uint b){ uint d; asm("v_pk_min_i16 %0, %1, %2" : "=v"(d) : "v"(a), "v"(b)); return d; }
__device__ __forceinline__ uint pk_sub16(uint a, uint b){ uint d; asm("v_pk_sub_i16 %0, %1, %2" : "=v"(d) : "v"(a), "v"(b)); return d; }
__device__ __forceinline__ uint mul24(uint a, uint b){ uint d; asm("v_mul_u32_u24 %0, %1, %2" : "=v"(d) : "v"(a), "v"(b)); return d; }

__device__ __forceinline__ void scan4(float4 q, int kbase, float& M, float& M2, int& mi)
{
  float v; bool c;
  v = q.x; c = v > M; M2 = c ? M : fmaxf(M2, v); M = c ? v : M; mi = c ? kbase + 0 : mi;
  v = q.y; c = v > M; M2 = c ? M : fmaxf(M2, v); M = c ? v : M; mi = c ? kbase + 1 : mi;
  v = q.z; c = v > M; M2 = c ? M : fmaxf(M2, v); M = c ? v : M; mi = c ? kbase + 2 : mi;
  v = q.w; c = v > M; M2 = c ? M : fmaxf(M2, v); M = c ? v : M; mi = c ? kbase + 3 : mi;
}

// 4 LANES per position, no LDS (round-11/12 version, best measured; 8-lane
// regressed in round 13). Lane 4g+r loads float4s {r, r+4, r+8, r+12, r+16}
// of row g: 16 cache lines per wave-load instruction (ideal-coalescing line
// count), 5 independent loads + ~60 VALU per lane. Leader's reg/ctr loads
// issued FIRST so that HBM round-trip overlaps the cls scan (r13 salvage).
// (M, M2, first-index argmax) merged across 4 lanes in 2 shfl_xor steps:
// tie -> min index == reference first-index; equal lane-maxes give M2=M ->
// exact slow path. Sigmoid fast path (validated bit-exact rounds 7-13):
// logit argmax == sigmoid argmax unless M2 within 8e-6/(1-s*) of M (>=8x
// safety over 3-ulp sigmoid error); rare fallback = exact reference-order
// sigmoid argmax on register-resident bufs, merged (larger s, tie smaller idx).
__global__ __launch_bounds__(256) void decode_kernel(Ptrs p, uint* wsu)
{
  const int t = threadIdx.x;
  const int wv = t >> 6, lane = t & 63;
  const int g = lane >> 2, r = lane & 3;
  const int wpos0 = blockIdx.x * 64 + wv * 16;    // wave's first position
  const int b = wpos0 / HW_TOTAL;
  const int hw0 = wpos0 - b * HW_TOTAL;           // wave-uniform level (16-pos aligned)

  const float *clsp, *regp, *ctrp;
  int lstart, lw, HWl; float stridef;
  if (hw0 < 16384)      { lstart = 0;     lw = 7; stridef = 8.f;   HWl = 16384; clsp = p.cls0; regp = p.reg0; ctrp = p.ctr0; }
  else if (hw0 < 20480) { lstart = 16384; lw = 6; stridef = 16.f;  HWl = 4096;  clsp = p.cls1; regp = p.reg1; ctrp = p.ctr1; }
  else if (hw0 < 21504) { lstart = 20480; lw = 5; stridef = 32.f;  HWl = 1024;  clsp = p.cls2; regp = p.reg2; ctrp = p.ctr2; }
  else if (hw0 < 21760) { lstart = 21504; lw = 4; stridef = 64.f;  HWl = 256;   clsp = p.cls3; regp = p.reg3; ctrp = p.ctr3; }
  else                  { lstart = 21760; lw = 3; stridef = 128.f; HWl = 64;    clsp = p.cls4; regp = p.reg4; ctrp = p.ctr4; }

  const long base = (long)b * HWl + (hw0 - lstart);   // level-local of wave's first pos
  const long row = base + g;                          // this group's level-local row
  const float4* c4 = reinterpret_cast<const float4*>(clsp) + row * 20;

  // leader's reg/ctr issued FIRST: latency overlaps the cls scan below
  float4 r4 = make_float4(0.f, 0.f, 0.f, 0.f);
  float ctrv = 0.f;
  if (r == 0) {
    r4 = reinterpret_cast<const float4*>(regp)[row];
    ctrv = ctrp[row];
  }

  // 5 independent loads; lane covers classes 4*(r+4j)+c, ascending in j
  float4 buf[5];
  #pragma unroll
  for (int j = 0; j < 5; ++j) buf[j] = c4[r + 4 * j];

  float M = -INFINITY, M2 = -INFINITY; int mi = 0;
  #pragma unroll
  for (int j = 0; j < 5; ++j) scan4(buf[j], 4 * (r + 4 * j), M, M2, mi);

  // merge (M, M2, mi) across the 4 lanes of the group (xor 1, then 2)
  #pragma unroll
  for (int ms_ = 1; ms_ <= 2; ms_ <<= 1) {
    float Mo  = __shfl_xor(M, ms_);
    float M2o = __shfl_xor(M2, ms_);
    int   mio = __shfl_xor(mi, ms_);
    float mn = fminf(M, Mo);
    M2 = fmaxf(mn, fmaxf(M2, M2o));                 // equal maxes -> M2 = M -> slow path
    bool take = (Mo > M) || (Mo == M && mio < mi);  // tie -> min index (first index)
    mi = take ? mio : mi;
    M  = fmaxf(M, Mo);
  }

  float sstar = sigmoidf_(M);
  float onem = 1.0f - sstar;
  float thr = (onem > 0.0f) ? (M - 8e-6f / onem) : INFINITY;   // INF -> forced slow path
  float msig = sstar; int mfin = mi;
  if (!(M2 < thr)) {
    // exact path: per-lane in-order sigmoid argmax (strict >), cross-lane
    // merge (larger s; tie -> smaller idx) == reference global first-index
    float ms = -1.f; int mj = 0;
    #pragma unroll
    for (int j = 0; j < 5; ++j) {
      float4 q = buf[j];
      int kb = 4 * (r + 4 * j);
      float s;
      s = sigmoidf_(q.x); if (s > ms) { ms = s; mj = kb + 0; }
      s = sigmoidf_(q.y); if (s > ms) { ms = s; mj = kb + 1; }
      s = sigmoidf_(q.z); if (s > ms) { ms = s; mj = kb + 2; }
      s = sigmoidf_(q.w); if (s > ms) { ms = s; mj = kb + 3; }
    }
    #pragma unroll
    for (int ms_ = 1; ms_ <= 2; ms_ <<= 1) {
      float mso = __shfl_xor(ms, ms_);
      int   mjo = __shfl_xor(mj, ms_);
      bool take = (mso > ms) || (mso == ms && mjo < mj);
      ms = take ? mso : ms;
      mj = take ? mjo : mj;
    }
    msig = ms; mfin = mj;
  }

  if (r == 0) {                       // group leader finishes the position
    float scv = sqrtf(msig * sigmoidf_(ctrv));

    int lhw = (hw0 - lstart) + g;
    int h = lhw >> lw, w = lhw - (h << lw);
    float x = ((float)w + 0.5f) * stridef;
    float y = ((float)h + 0.5f) * stridef;
    float x1 = fmaxf(truncf(x - expf(r4.x)), 0.f);
    float y1 = fmaxf(truncf(y - expf(r4.y)), 0.f);
    float x2 = fminf(truncf(x + expf(r4.z)), 1023.f);
    float y2 = fminf(truncf(y + expf(r4.w)), 1023.f);

    // key: monotone u26 form of score; 0 = dead (masking pre-topk is output-equivalent)
    uint kraw = (scv > 0.05f) ? (__float_as_uint(scv) - 0x3D000000u) : 0u;
    uint ix1 = (uint)x1, iy1 = (uint)y1, ix2 = (uint)x2, iy2 = (uint)y2;
    uint2 pb = make_uint2(ix1 | (iy1 << 16), ix2 | (iy2 << 16));

    int idx = wpos0 + g;
    int hw = hw0 + g;
    float* wsf = (float*)wsu;
    wsu[FULL_KEY + idx] = kraw;
    wsf[FULL_CLS + idx] = (float)mfin;
    reinterpret_cast<uint2*>(wsu + FULL_PBOX)[idx] = pb;

    // levels 3/4 skip top-k (HW < TOP_N): write candidate slices directly
    if (hw >= 21504) {
      int ci = b * NCAND + 3000 + (hw - 21504);
      wsu[CAND_KEY + ci] = kraw;
      wsf[CAND_CLS + ci] = (float)mfin;
      reinterpret_cast<uint2*>(wsu + CAND_PBOX)[ci] = pb;
    }
  }
}

// exclusive block scan over 1024 threads; also returns grand total.
// Internal barriers; safe to call repeatedly (barrier precedes partials write).
__device__ __forceinline__ uint block_scan_excl(uint v, uint* partials, uint& total)
{
  int lane = threadIdx.x & 63, wv = threadIdx.x >> 6;
  uint incl = v;
  #pragma unroll
  for (int m = 1; m < 64; m <<= 1) {
    uint u = __shfl_up(incl, m);
    if (lane >= m) incl += u;
  }
  __syncthreads();
  if (lane == 63) partials[wv] = incl;
  __syncthreads();
  uint wpre = 0, tot = 0;
  #pragma unroll
  for (int w = 0; w < 16; ++w) {
    uint pv = partials[w];
    if (w < wv) wpre += pv;
    tot += pv;
  }
  total = tot;
  return wpre + incl - v;
}

// exact top-k per (batch, level): keys register-resident; exact K-th-largest
// key via 2-pass 13-bit radix-select (~14 block barriers); then >lo all +
// ==lo in index order (== lax.top_k set). Radix lo == binary-search lo
// (dead keys participate as value 0).
template<int CH, int HW, int K>
__device__ void topk_impl(const uint* __restrict__ fsu, const float* __restrict__ fc,
                          const uint2* __restrict__ fpb,
                          uint* __restrict__ cs, float* __restrict__ cc,
                          uint2* __restrict__ cpb,
                          uint* scratch, uint* partials, int* part, uint* selsh)
{
  int t = threadIdx.x, lane = t & 63, wid = t >> 6;

  uint key[CH];
  constexpr int HALF = (HW > 8192) ? 8192 : HW;   // staging tile (<= 32KB LDS)
  constexpr int ROUNDS = HW / HALF;
  #pragma unroll
  for (int rr = 0; rr < ROUNDS; ++rr) {
    int base = rr * HALF;
    for (int i = t; i < HALF; i += 1024)          // coalesced global read
      scratch[i] = fsu[base + i];
    __syncthreads();
    int t0 = base / CH;
    if (t >= t0 && t < t0 + HALF / CH) {          // redistribute: contiguous chunk per thread
      int off = t * CH - base;
      #pragma unroll
      for (int k = 0; k < CH; ++k) key[k] = scratch[off + k];
    }
    __syncthreads();
  }

  // ---- radix-select: lo = exact K-th largest key (keys are 26-bit) ----
  // pass 1: histogram of key>>13 (buckets 0..8191); reversed scan -> bucket T
  for (int i = t; i < 8192; i += 1024) scratch[i] = 0u;
  __syncthreads();
  #pragma unroll
  for (int k = 0; k < CH; ++k) atomicAdd(&scratch[key[k] >> 13], 1u);
  __syncthreads();
  uint c8[8], s = 0;
  #pragma unroll
  for (int j = 0; j < 8; ++j) { c8[j] = scratch[8191 - (t * 8 + j)]; s += c8[j]; }
  uint total;
  uint cum = block_scan_excl(s, partials, total);  // count in buckets above mine
  #pragma unroll
  for (int j = 0; j < 8; ++j) {                    // exactly one thread crosses
    if (cum < (uint)K && cum + c8[j] >= (uint)K) {
      selsh[0] = (uint)(8191 - (t * 8 + j));       // T
      selsh[1] = cum;                              // count of keys with prefix > T
    }
    cum += c8[j];
  }
  __syncthreads();                                 // selsh visible; pass-1 reads done
  const uint T = selsh[0];
  const uint Kp = (uint)K - selsh[1];              // rank within bucket T (1-based)

  // pass 2: histogram of low 13 bits within bucket T; reversed scan -> L
  for (int i = t; i < 8192; i += 1024) scratch[i] = 0u;
  __syncthreads();
  #pragma unroll
  for (int k = 0; k < CH; ++k)
    if ((key[k] >> 13) == T) atomicAdd(&scratch[key[k] & 0x1FFFu], 1u);
  __syncthreads();
  uint d8[8], s2 = 0;
  #pragma unroll
  for (int j = 0; j < 8; ++j) { d8[j] = scratch[8191 - (t * 8 + j)]; s2 += d8[j]; }
  uint tot2;
  uint cum2 = block_scan_excl(s2, partials, tot2);
  #pragma unroll
  for (int j = 0; j < 8; ++j) {
    if (cum2 < Kp && cum2 + d8[j] >= Kp) selsh[2] = (uint)(8191 - (t * 8 + j));
    cum2 += d8[j];
  }
  __syncthreads();
  const uint lo = (T << 13) | selsh[2];

  // ranks: count(>lo) all selected (index order), then ==lo fills to K (index order)
  int cgt = 0, ceq = 0;
  #pragma unroll
  for (int k = 0; k < CH; ++k) { cgt += (key[k] > lo) ? 1 : 0; ceq += (key[k] == lo) ? 1 : 0; }
  uint packed = ((uint)cgt << 16) | (uint)ceq;
  uint incl = packed;
  #pragma unroll
  for (int m = 1; m < 64; m <<= 1) {
    uint u = __shfl_up(incl, m);
    if (lane >= m) incl += u;
  }
  __syncthreads();
  if (lane == 63) part[wid] = (int)incl;
  __syncthreads();
  uint wpre = 0, tot_all = 0;
  #pragma unroll
  for (int w = 0; w < 16; ++w) {
    uint pv = (uint)part[w];
    if (w < wid) wpre += pv;
    tot_all += pv;
  }
  uint excl = wpre + incl - packed;
  int rgt = (int)(excl >> 16);
  int req = (int)(tot_all >> 16) + (int)(excl & 0xFFFFu);

  #pragma unroll
  for (int k = 0; k < CH; ++k) {
    int i = t * CH + k;
    uint kk = key[k];
    int r = -1;
    if (kk > lo) r = rgt++;
    else if (kk == lo) r = req++;
    if (r >= 0 && r < K) {
      cs[r] = kk;
      cc[r] = fc[i];
      cpb[r] = fpb[i];
    }
  }
}

__global__ __launch_bounds__(1024) void topk_kernel(uint* wsu)
{
  __shared__ uint scratch[8192];   // staging, then radix histograms (32 KB)
  __shared__ uint partials[16];
  __shared__ int part[16];
  __shared__ uint selsh[4];
  int b = blockIdx.x, lvl = blockIdx.y;
  int lstart, coff;
  if (lvl == 0)      { lstart = 0;     coff = 0;    }
  else if (lvl == 1) { lstart = 16384; coff = 1000; }
  else               { lstart = 20480; coff = 2000; }
  int fbase = b * HW_TOTAL + lstart;
  const uint* fsu = wsu + FULL_KEY + fbase;
  const float* fc = ((const float*)wsu) + FULL_CLS + fbase;
  const uint2* fpb = reinterpret_cast<const uint2*>(wsu + FULL_PBOX) + fbase;
  uint*  cs = wsu + CAND_KEY + b * NCAND + coff;
  float* cc = ((float*)wsu) + CAND_CLS + b * NCAND + coff;
  uint2* cpb = reinterpret_cast<uint2*>(wsu + CAND_PBOX) + b * NCAND + coff;

  if (lvl == 0)      topk_impl<16, 16384, 1000>(fsu, fc, fpb, cs, cc, cpb, scratch, partials, part, selsh);
  else if (lvl == 1) topk_impl<4,  4096,  1000>(fsu, fc, fpb, cs, cc, cpb, scratch, partials, part, selsh);
  else               topk_impl<1,  1024,  1000>(fsu, fc, fpb, cs, cc, cpb, scratch, partials, part, selsh);
}

// ---- bitonic helpers ----
__device__ __forceinline__ u64 shfl_xor_u64(u64 v, int m) {
  int lo = __shfl_xor((int)(uint)(v & 0xffffffffull), m);
  int hi = __shfl_xor((int)(uint)(v >> 32), m);
  return ((u64)(uint)hi << 32) | (u64)(uint)lo;
}
__device__ __forceinline__ u64 ce_shfl(u64 v, int j, bool up, int lane) {
  u64 p = shfl_xor_u64(v, j);
  bool keep_max = (((lane & j) == 0) == up);
  return keep_max ? (v > p ? v : p) : (v < p ? v : p);
}
__device__ __forceinline__ u64 ce_lds(u64 v, u64 p, uint i, uint j, uint k) {
  bool keep_max = (((i & j) == 0u) == ((i & k) == 0u));
  return keep_max ? (v > p ? v : p) : (v < p ? v : p);
}

// Preselect + sort + lazy greedy NMS, one block per batch (round-6 design,
// passing absmax 0; see earlier round comments for the equivalence proofs).
__global__ __launch_bounds__(1024) void nms_kernel(const uint* __restrict__ wsu,
                                                   float* __restrict__ out)
{
  __shared__ uint hist[4096];      // 16 KB
  __shared__ u64 items[1024];      // 8 KB
  __shared__ uint2 boxo[3328];     // 26 KB, indexed by original slot
  __shared__ uint partials[16];
  __shared__ int bsel_sh;

  const int b = blockIdx.x, t = threadIdx.x;
  const int lane = t & 63;
  const uint*  ck  = wsu + CAND_KEY + b * NCAND;
  const float* ccl = ((const float*)wsu) + CAND_CLS + b * NCAND;
  const uint2* cpb = reinterpret_cast<const uint2*>(wsu + CAND_PBOX) + b * NCAND;

  // load keys (regs) + boxes (LDS), coalesced
  uint k0 = (t          < NCAND) ? ck[t]          : 0u;
  uint k1 = (t + 1024   < NCAND) ? ck[t + 1024]   : 0u;
  uint k2 = (t + 2048   < NCAND) ? ck[t + 2048]   : 0u;
  uint k3 = (t + 3072   < NCAND) ? ck[t + 3072]   : 0u;
  for (int i = t; i < 3328; i += 1024)
    boxo[i] = (i < NCAND) ? cpb[i] : make_uint2(0u, 0u);

  reinterpret_cast<uint4*>(hist)[t] = make_uint4(0u, 0u, 0u, 0u);
  if (t == 0) bsel_sh = 0;
  __syncthreads();

  if (k0) atomicAdd(&hist[k0 >> 14], 1u);
  if (k1) atomicAdd(&hist[k1 >> 14], 1u);
  if (k2) atomicAdd(&hist[k2 >> 14], 1u);
  if (k3) atomicAdd(&hist[k3 >> 14], 1u);
  __syncthreads();

  // reversed cumulative (from highest bucket down); find bucket of 512th key
  uint c[4]; uint s = 0;
  #pragma unroll
  for (int q = 0; q < 4; ++q) { c[q] = hist[4095 - (t * 4 + q)]; s += c[q]; }
  uint total;
  uint excl = block_scan_excl(s, partials, total);
  {
    uint cum = excl;
    #pragma unroll
    for (int q = 0; q < 4; ++q) {
      if (total >= 512u && cum < 512u && cum + c[q] >= 512u)
        bsel_sh = 4095 - (t * 4 + q);
      cum += c[q];
    }
  }
  __syncthreads();
  const uint B = (uint)bsel_sh;

  // compact the >=B slice into items[]
  bool s0 = k0 && (k0 >> 14) >= B;
  bool s1 = k1 && (k1 >> 14) >= B;
  bool s2 = k2 && (k2 >> 14) >= B;
  bool s3 = k3 && (k3 >> 14) >= B;
  uint nsel = (uint)s0 + (uint)s1 + (uint)s2 + (uint)s3;
  items[t] = 0ull;
  uint tot2;
  uint pos = block_scan_excl(nsel, partials, tot2);
  if (s0) { if (pos < 1024u) items[pos] = ((u64)k0 << 32) | (u64)(0xFFFFu - (uint)t);          ++pos; }
  if (s1) { if (pos < 1024u) items[pos] = ((u64)k1 << 32) | (u64)(0xFFFFu - (uint)(t + 1024)); ++pos; }
  if (s2) { if (pos < 1024u) items[pos] = ((u64)k2 << 32) | (u64)(0xFFFFu - (uint)(t + 2048)); ++pos; }
  if (s3) { if (pos < 1024u) items[pos] = ((u64)k3 << 32) | (u64)(0xFFFFu - (uint)(t + 3072)); ++pos; }
  __syncthreads();

  // bitonic sort of 1024 items, descending; 1 item/thread
  u64 r = items[t];
  for (uint kk = 2; kk <= 1024; kk <<= 1) {
    for (uint j = kk >> 1; j > 0; j >>= 1) {
      if (j >= 64u) {
        items[t] = r;
        __syncthreads();
        u64 p = items[t ^ (int)j];
        r = ce_lds(r, p, (uint)t, j, kk);
        __syncthreads();
      } else {
        r = ce_shfl(r, (int)j, ((uint)t & kk) == 0u, lane);
      }
    }
  }
  items[t] = r;
  __syncthreads();

  if (t >= 64) return;               // scan + writeout are wave-0 only

  uint sax = 0u, say = 0u, sa3a = 0u;     // selected box (index == lane)
  uint sbx = 0u, sby = 0u, sa3b = 0u;     // selected box (index == 64+lane)
  uint rrank0 = 0xFFFFFFFFu, rrank1 = 0xFFFFFFFFu;
  int m = 0;
  bool done = false;

  for (int base = 0; base < 1024 && !done && m < MAXDET; base += 64) {
    u64 it = items[base + lane];
    uint mykey = (uint)(it >> 32);
    int myslot = 0xFFFF - (int)(it & 0xFFFFu);
    if (myslot > 3327) myslot = 0;         // dead lanes: clamp (value unused)
    uint2 mb = boxo[myslot];
    uint mwh = pk_sub16(mb.y, mb.x);
    uint mqa3 = 3u * mul24(mwh & 0xffffu, mwh >> 16);

    u64 deadmask = __ballot(mykey == 0u);  // sorted: dead lanes are a suffix
    int nv = deadmask ? (__ffsll((long long)deadmask) - 1) : 64;
    if (nv < 64) done = true;

    for (int s = 0; s < nv; ++s) {
      uint qx  = (uint)__builtin_amdgcn_readlane((int)mb.x, s);
      uint qy  = (uint)__builtin_amdgcn_readlane((int)mb.y, s);
      uint qa3 = (uint)__builtin_amdgcn_readlane((int)mqa3, s);

      uint tl = pk_max16(qx, sax), br = pk_min16(qy, say);
      uint wh = pk_max16(pk_sub16(br, tl), 0u);
      uint inter = mul24(wh & 0xffffu, wh >> 16);
      uint s3 = qa3 + sa3a; uint s3m = s3 > 1u ? s3 : 1u;
      bool sup0 = (lane < m) && ((inter << 3) >= s3m);

      tl = pk_max16(qx, sbx); br = pk_min16(qy, sby);
      wh = pk_max16(pk_sub16(br, tl), 0u);
      inter = mul24(wh & 0xffffu, wh >> 16);
      s3 = qa3 + sa3b; s3m = s3 > 1u ? s3 : 1u;
      bool sup1 = ((64 + lane) < m) && ((inter << 3) >= s3m);

      if (__ballot(sup0 || sup1) == 0ull) {    // SELECT rank base+s
        int rank = base + s;
        if (m < 64) {
          if (lane == m)      { sax = qx; say = qy; sa3a = qa3; rrank0 = (uint)rank; }
        } else {
          if (lane == m - 64) { sbx = qx; sby = qy; sa3b = qa3; rrank1 = (uint)rank; }
        }
        ++m;
        if (m >= MAXDET) break;
      }
    }
  }

  // writeout: lane l -> detection l (rrank0) and 64+l (rrank1, l<36)
  float* outs = out;
  float* outc = out + BATCH * MAXDET;
  float4* outb = reinterpret_cast<float4*>(out + 2 * BATCH * MAXDET);
  {
    float s, cl; float4 bx;
    if (rrank0 != 0xFFFFFFFFu) {
      u64 it = items[rrank0];
      uint key = (uint)(it >> 32);
      int slot = 0xFFFF - (int)(it & 0xFFFFu);
      uint2 q = boxo[slot];
      s = __uint_as_float(key + 0x3D000000u);
      cl = ccl[slot];
      bx = make_float4((float)(q.x & 0xffffu), (float)(q.x >> 16),
                       (float)(q.y & 0xffffu), (float)(q.y >> 16));
    } else { s = -1.f; cl = -1.f; bx = make_float4(-1.f, -1.f, -1.f, -1.f); }
    outs[b * MAXDET + lane] = s;
    outc[b * MAXDET + lane] = cl;
    outb[b * MAXDET + lane] = bx;
  }
  if (lane < MAXDET - 64) {
    float s, cl; float4 bx;
    if (rrank1 != 0xFFFFFFFFu) {
      u64 it = items[rrank1];
      uint key = (uint)(it >> 32);
      int slot = 0xFFFF - (int)(it & 0xFFFFu);
      uint2 q = boxo[slot];
      s = __uint_as_float(key + 0x3D000000u);
      cl = ccl[slot];
      bx = make_float4((float)(q.x & 0xffffu), (float)(q.x >> 16),
                       (float)(q.y & 0xffffu), (float)(q.y >> 16));
    } else { s = -1.f; cl = -1.f; bx = make_float4(-1.f, -1.f, -1.f, -1.f); }
    outs[b * MAXDET + 64 + lane] = s;
    outc[b * MAXDET + 64 + lane] = cl;
    outb[b * MAXDET + 64 + lane] = bx;
  }
}

extern "C" void kernel_launch(void* const* d_in, const int* in_sizes, int n_in,
                              void* d_out, int out_size, void* d_ws, size_t ws_size,
                              hipStream_t stream)
{
  Ptrs p;
  p.cls0 = (const float*)d_in[0];  p.reg0 = (const float*)d_in[1];  p.ctr0 = (const float*)d_in[2];
  p.cls1 = (const float*)d_in[3];  p.reg1 = (const float*)d_in[4];  p.ctr1 = (const float*)d_in[5];
  p.cls2 = (const float*)d_in[6];  p.reg2 = (const float*)d_in[7];  p.ctr2 = (const float*)d_in[8];
  p.cls3 = (const float*)d_in[9];  p.reg3 = (const float*)d_in[10]; p.ctr3 = (const float*)d_in[11];
  p.cls4 = (const float*)d_in[12]; p.reg4 = (const float*)d_in[13]; p.ctr4 = (const float*)d_in[14];

  uint* wsu = (uint*)d_ws;
  float* out = (float*)d_out;

  // 4 lanes/position: 1396736 threads = 5456 blocks x 256
  decode_kernel<<<(4 * BATCH * HW_TOTAL) / 256, 256, 0, stream>>>(p, wsu);
  dim3 g2(BATCH, 3);
  topk_kernel<<<g2, 1024, 0, stream>>>(wsu);
  nms_kernel<<<BATCH, 1024, 0, stream>>>(wsu, out);
}